// Round 4
// baseline (788.209 us; speedup 1.0000x reference)
//
#include <hip/hip_runtime.h>
#include <hip/hip_bf16.h>
#include <math.h>

#define IDIM 512
#define HDIM 64

// CSR build: (src-slice, dst-bucket) counting sort
#define CB_SH 9               // dst bucket = dst >> 9 (512 nodes)
#define NSB 4                 // src slices (table slice ~3.05MB < 4MB L2)
#define PCHUNK 4096           // edges per partition block

typedef __attribute__((ext_vector_type(8))) short short8;   // 8 bf16 = 4 VGPRs
typedef __attribute__((ext_vector_type(4))) float f32x4;    // MFMA accum
typedef __attribute__((ext_vector_type(4))) float f4;
typedef unsigned short u16;
typedef unsigned int u32;

__device__ __forceinline__ float bflo(u32 u) { return __uint_as_float(u << 16); }
__device__ __forceinline__ float bfhi(u32 u) { return __uint_as_float(u & 0xffff0000u); }
__device__ __forceinline__ f4 ntload4(const float* p) { return __builtin_nontemporal_load((const f4*)p); }
__device__ __forceinline__ void ntstore4(float* p, f4 v) { __builtin_nontemporal_store(v, (f4*)p); }

// ============ (1) histogram of key = (src/Q)*NBd + (dst>>CB_SH) ============
__global__ __launch_bounds__(256) void k_chist(const int* __restrict__ src,
                                               const int* __restrict__ dst,
                                               int* __restrict__ gHist, int E,
                                               int NBK, int NBd, int Q) {
    __shared__ int h[1024];
    int tid = threadIdx.x;
    for (int i = tid; i < NBK; i += 256) h[i] = 0;
    __syncthreads();
    int stride = gridDim.x * 256;
    for (int e = blockIdx.x * 256 + tid; e < E; e += stride) {
        int key = (src[e] / Q) * NBd + (dst[e] >> CB_SH);
        atomicAdd(&h[key], 1);
    }
    __syncthreads();
    for (int i = tid; i < NBK; i += 256)
        if (h[i]) atomicAdd(&gHist[i], h[i]);
}

// ============ (2) scan keys; emit bucketBase/gcur + per-slice rowptr sentinels
__global__ __launch_bounds__(256) void k_cscan(const int* __restrict__ gHist,
                                               int* __restrict__ bucketBase,
                                               int* __restrict__ gcur, int NBK, int NBd,
                                               int* __restrict__ rowptr4, int n, int E) {
    __shared__ int ss[256];
    int tid = threadIdx.x;
    int v[4];
    int s = 0;
#pragma unroll
    for (int k = 0; k < 4; k++) {
        int i = tid * 4 + k;
        v[k] = (i < NBK) ? gHist[i] : 0;
        s += v[k];
    }
    ss[tid] = s;
    __syncthreads();
    for (int o = 1; o < 256; o <<= 1) {
        int u = (tid >= o) ? ss[tid - o] : 0;
        __syncthreads();
        ss[tid] += u;
        __syncthreads();
    }
    int ex = ss[tid] - s;
#pragma unroll
    for (int k = 0; k < 4; k++) {
        int i = tid * 4 + k;
        if (i < NBK) {
            bucketBase[i] = ex;
            gcur[i] = ex;
            // slice boundary: start of slice sb -> sentinel of slice sb-1
            if (i > 0 && (i % NBd) == 0)
                rowptr4[(size_t)(i / NBd - 1) * (n + 1) + n] = ex;
        }
        ex += v[k];
    }
    if (tid == 0) {
        bucketBase[NBK] = E;
        rowptr4[(size_t)(NSB - 1) * (n + 1) + n] = E;
    }
}

// ============ (3) partition edges into key-contiguous tmp pairs ============
__global__ __launch_bounds__(256) void k_partition(const int* __restrict__ src,
                                                   const int* __restrict__ dst,
                                                   int* __restrict__ gcur,
                                                   int2* __restrict__ tmp, int E,
                                                   int NBK, int NBd, int Q) {
    __shared__ int h[1024];
    __shared__ int base[1024];
    int tid = threadIdx.x;
    int e0 = blockIdx.x * PCHUNK;
    int e1 = min(e0 + PCHUNK, E);
    for (int i = tid; i < NBK; i += 256) h[i] = 0;
    __syncthreads();
    for (int e = e0 + tid; e < e1; e += 256) {
        int key = (src[e] / Q) * NBd + (dst[e] >> CB_SH);
        atomicAdd(&h[key], 1);
    }
    __syncthreads();
    for (int i = tid; i < NBK; i += 256) {
        int c = h[i];
        base[i] = c ? atomicAdd(&gcur[i], c) : 0;
        h[i] = 0;   // reuse as running cursor
    }
    __syncthreads();
    for (int e = e0 + tid; e < e1; e += 256) {
        int sv = src[e], d = dst[e];
        int key = (sv / Q) * NBd + (d >> CB_SH);
        int r = atomicAdd(&h[key], 1);
        tmp[base[key] + r] = make_int2(sv, d);
    }
}

// ============ (4) per-key finalize: local sort by dst, write rowptr4 + srcs ==
__global__ __launch_bounds__(256) void k_finalize(const int2* __restrict__ tmp,
                                                  const int* __restrict__ bucketBase,
                                                  int* __restrict__ rowptr4,
                                                  int* __restrict__ srcs, int n, int NBd) {
    __shared__ int hist[1 << CB_SH];
    __shared__ int off[1 << CB_SH];
    __shared__ int ss[256];
    int key = blockIdx.x;
    int sb = key / NBd, db = key % NBd;
    int tid = threadIdx.x;
    int node0 = db << CB_SH;
    int nloc = min(1 << CB_SH, n - node0);
    int e0 = bucketBase[key], e1 = bucketBase[key + 1];
    hist[tid] = 0;
    hist[tid + 256] = 0;
    __syncthreads();
    for (int e = e0 + tid; e < e1; e += 256)
        atomicAdd(&hist[tmp[e].y - node0], 1);
    __syncthreads();
    int v0 = hist[2 * tid], v1 = hist[2 * tid + 1];
    int ps = v0 + v1;
    ss[tid] = ps;
    __syncthreads();
    for (int o = 1; o < 256; o <<= 1) {
        int u = (tid >= o) ? ss[tid - o] : 0;
        __syncthreads();
        ss[tid] += u;
        __syncthreads();
    }
    int ex = ss[tid] - ps;
    off[2 * tid] = ex;
    off[2 * tid + 1] = ex + v0;
    __syncthreads();
    int* rp = rowptr4 + (size_t)sb * (n + 1);
    for (int i = tid; i < nloc; i += 256)
        rp[node0 + i] = e0 + off[i];
    __syncthreads();
    for (int e = e0 + tid; e < e1; e += 256) {
        int2 p = tmp[e];
        int r = atomicAdd(&off[p.y - node0], 1);
        srcs[e0 + r] = p.x;
    }
}

// ============ dinv from per-slice rowptr diffs ============
__global__ __launch_bounds__(256) void k_dinv(const int* __restrict__ rowptr4,
                                              float* __restrict__ dinv, int n) {
    int i = blockIdx.x * 256 + threadIdx.x;
    if (i >= n) return;
    int d = 0;
#pragma unroll
    for (int sb = 0; sb < NSB; sb++) {
        const int* rp = rowptr4 + (size_t)sb * (n + 1);
        d += rp[i + 1] - rp[i];
    }
    dinv[i] = rsqrtf((float)d + 1.0f);
}

// ============ W1 -> bf16 B^T table ============
__global__ __launch_bounds__(256) void k_prepB(const float* __restrict__ W1,
                                               short* __restrict__ Btg) {
    int id = blockIdx.x * 256 + threadIdx.x;
    if (id >= IDIM * HDIM) return;
    int k = id >> 6, nn = id & 63;
    __hip_bfloat16 b = __float2bfloat16(W1[id]);
    Btg[nn * IDIM + k] = *(short*)&b;
}

// ============ [Wmu|Wvar] -> bf16 hi/lo B^T tables ============
__global__ __launch_bounds__(256) void k_prepW2(const float* __restrict__ Wmu,
                                                const float* __restrict__ Wvar,
                                                short* __restrict__ Whi,
                                                short* __restrict__ Wlo) {
    int id = blockIdx.x * 256 + threadIdx.x;
    if (id >= 128 * 64) return;
    int c = id >> 6;
    int k = id & 63;
    float wv = (c < 64) ? Wmu[k * 64 + c] : Wvar[k * 64 + (c - 64)];
    __hip_bfloat16 h = __float2bfloat16(wv);
    float hf = __bfloat162float(h);
    __hip_bfloat16 l = __float2bfloat16(wv - hf);
    Whi[c * 64 + k] = *(short*)&h;
    Wlo[c * 64 + k] = *(short*)&l;
}

// ============ GEMM1 (bf16 MFMA): g1 = bf16((x @ W1) * dinv), dense [n][64] ===
#define GM 128
#define KC 64
#define APAD 8
__global__ __launch_bounds__(256) void k_gemm1(const float* __restrict__ x,
                                               const short* __restrict__ Btg,
                                               const float* __restrict__ dinv,
                                               u16* __restrict__ g1, int n) {
    __shared__ short As[GM][KC + APAD];
    __shared__ short Bs[HDIM][KC + APAD];
    int tid = threadIdx.x;
    int row0 = blockIdx.x * GM;
    int w = tid >> 6, lane = tid & 63;
    int m = lane & 15, kb = lane >> 4;

    f32x4 acc[2][4];
#pragma unroll
    for (int rb = 0; rb < 2; rb++)
#pragma unroll
        for (int nt = 0; nt < 4; nt++) acc[rb][nt] = (f32x4){0.f, 0.f, 0.f, 0.f};

    for (int kc = 0; kc < IDIM; kc += KC) {
        __syncthreads();
#pragma unroll
        for (int i = 0; i < 8; i++) {
            int idx = tid + i * 256;
            int r = idx >> 4;
            int c4 = idx & 15;
            int grow = row0 + r;
            float4 v = make_float4(0.f, 0.f, 0.f, 0.f);
            if (grow < n) v = *(const float4*)&x[(size_t)grow * IDIM + kc + c4 * 4];
            __hip_bfloat162 h0 = __float22bfloat162_rn(make_float2(v.x, v.y));
            __hip_bfloat162 h1 = __float22bfloat162_rn(make_float2(v.z, v.w));
            int2 p;
            p.x = *(int*)&h0;
            p.y = *(int*)&h1;
            *(int2*)&As[r][c4 * 4] = p;
        }
#pragma unroll
        for (int i = 0; i < 2; i++) {
            int idx = tid + i * 256;
            int r = idx >> 3;
            int u8 = idx & 7;
            float4 v = *(const float4*)&Btg[(size_t)r * IDIM + kc + u8 * 8];
            *(float4*)&Bs[r][u8 * 8] = v;
        }
        __syncthreads();
#pragma unroll
        for (int ks = 0; ks < KC; ks += 32) {
            short8 a0 = *(const short8*)&As[w * 32 + m][ks + kb * 8];
            short8 a1 = *(const short8*)&As[w * 32 + 16 + m][ks + kb * 8];
            short8 b0 = *(const short8*)&Bs[m][ks + kb * 8];
            short8 b1 = *(const short8*)&Bs[16 + m][ks + kb * 8];
            short8 b2 = *(const short8*)&Bs[32 + m][ks + kb * 8];
            short8 b3 = *(const short8*)&Bs[48 + m][ks + kb * 8];
            acc[0][0] = __builtin_amdgcn_mfma_f32_16x16x32_bf16(a0, b0, acc[0][0], 0, 0, 0);
            acc[0][1] = __builtin_amdgcn_mfma_f32_16x16x32_bf16(a0, b1, acc[0][1], 0, 0, 0);
            acc[0][2] = __builtin_amdgcn_mfma_f32_16x16x32_bf16(a0, b2, acc[0][2], 0, 0, 0);
            acc[0][3] = __builtin_amdgcn_mfma_f32_16x16x32_bf16(a0, b3, acc[0][3], 0, 0, 0);
            acc[1][0] = __builtin_amdgcn_mfma_f32_16x16x32_bf16(a1, b0, acc[1][0], 0, 0, 0);
            acc[1][1] = __builtin_amdgcn_mfma_f32_16x16x32_bf16(a1, b1, acc[1][1], 0, 0, 0);
            acc[1][2] = __builtin_amdgcn_mfma_f32_16x16x32_bf16(a1, b2, acc[1][2], 0, 0, 0);
            acc[1][3] = __builtin_amdgcn_mfma_f32_16x16x32_bf16(a1, b3, acc[1][3], 0, 0, 0);
        }
    }
#pragma unroll
    for (int rb = 0; rb < 2; rb++) {
        int rbase = row0 + w * 32 + rb * 16 + kb * 4;
#pragma unroll
        for (int reg = 0; reg < 4; reg++) {
            int grow = rbase + reg;
            if (grow < n) {
                float dv = dinv[grow];
#pragma unroll
                for (int nt = 0; nt < 4; nt++) {
                    __hip_bfloat16 b = __float2bfloat16(acc[rb][nt][reg] * dv);
                    g1[(size_t)grow * HDIM + nt * 16 + m] = *(u16*)&b;
                }
            }
        }
    }
}

// ============ layer-1 gather pass (src-slice sb) ============
// table rows read in this pass are confined to slice [sb*Q,(sb+1)*Q): L2-resident.
// srcs + fp32 accumulator use non-temporal accesses to avoid evicting the slice.
__global__ __launch_bounds__(256) void k_g1pass(const int* __restrict__ rowptr4,
                                                const int* __restrict__ srcs,
                                                const float* __restrict__ dinv,
                                                const u16* __restrict__ g1,
                                                const float* __restrict__ b1,
                                                float* __restrict__ acc1,
                                                u16* __restrict__ g2, int n,
                                                int pass, int isFirst, int isLast) {
    const int* rp = rowptr4 + (size_t)pass * (n + 1);
    int tid = threadIdx.x;
    int r = tid >> 6, lane = tid & 63;
    int grp = lane >> 3, q = lane & 7;
    int i = blockIdx.x * 4 + r;
    if (i >= n) return;
    int beg = rp[i], end = rp[i + 1];
    float a[8];
#pragma unroll
    for (int k = 0; k < 8; k++) a[k] = 0.f;
    int j = beg + grp;
    for (; j + 8 < end; j += 16) {
        int s0 = __builtin_nontemporal_load(&srcs[j]);
        int s1 = __builtin_nontemporal_load(&srcs[j + 8]);
        uint4 u0 = *(const uint4*)&g1[(size_t)s0 * HDIM + q * 8];
        uint4 u1 = *(const uint4*)&g1[(size_t)s1 * HDIM + q * 8];
        a[0] += bflo(u0.x) + bflo(u1.x); a[1] += bfhi(u0.x) + bfhi(u1.x);
        a[2] += bflo(u0.y) + bflo(u1.y); a[3] += bfhi(u0.y) + bfhi(u1.y);
        a[4] += bflo(u0.z) + bflo(u1.z); a[5] += bfhi(u0.z) + bfhi(u1.z);
        a[6] += bflo(u0.w) + bflo(u1.w); a[7] += bfhi(u0.w) + bfhi(u1.w);
    }
    if (j < end) {
        int s0 = __builtin_nontemporal_load(&srcs[j]);
        uint4 u0 = *(const uint4*)&g1[(size_t)s0 * HDIM + q * 8];
        a[0] += bflo(u0.x); a[1] += bfhi(u0.x);
        a[2] += bflo(u0.y); a[3] += bfhi(u0.y);
        a[4] += bflo(u0.z); a[5] += bfhi(u0.z);
        a[6] += bflo(u0.w); a[7] += bfhi(u0.w);
    }
#pragma unroll
    for (int k = 0; k < 8; k++) {
        a[k] += __shfl_xor(a[k], 8);
        a[k] += __shfl_xor(a[k], 16);
        a[k] += __shfl_xor(a[k], 32);
    }
    if (grp == 0) {
        size_t base = (size_t)i * HDIM + q * 8;
        if (!isFirst) {
            f4 p0 = ntload4(&acc1[base]);
            f4 p1 = ntload4(&acc1[base + 4]);
            a[0] += p0[0]; a[1] += p0[1]; a[2] += p0[2]; a[3] += p0[3];
            a[4] += p1[0]; a[5] += p1[1]; a[6] += p1[2]; a[7] += p1[3];
        }
        if (!isLast) {
            f4 s0v = {a[0], a[1], a[2], a[3]};
            f4 s1v = {a[4], a[5], a[6], a[7]};
            ntstore4(&acc1[base], s0v);
            ntstore4(&acc1[base + 4], s1v);
        } else {
            uint4 us = *(const uint4*)&g1[base];   // self row (coalesced over i)
            float s0 = bflo(us.x), s1 = bfhi(us.x), s2 = bflo(us.y), s3 = bfhi(us.y);
            float s4 = bflo(us.z), s5 = bfhi(us.z), s6 = bflo(us.w), s7 = bfhi(us.w);
            float4 bv0 = *(const float4*)&b1[q * 8];
            float4 bv1 = *(const float4*)&b1[q * 8 + 4];
            float di = dinv[i];
            float o0 = fmaxf(di * (a[0] + s0) + bv0.x, 0.f) * di;
            float o1 = fmaxf(di * (a[1] + s1) + bv0.y, 0.f) * di;
            float o2 = fmaxf(di * (a[2] + s2) + bv0.z, 0.f) * di;
            float o3 = fmaxf(di * (a[3] + s3) + bv0.w, 0.f) * di;
            float o4 = fmaxf(di * (a[4] + s4) + bv1.x, 0.f) * di;
            float o5 = fmaxf(di * (a[5] + s5) + bv1.y, 0.f) * di;
            float o6 = fmaxf(di * (a[6] + s6) + bv1.z, 0.f) * di;
            float o7 = fmaxf(di * (a[7] + s7) + bv1.w, 0.f) * di;
            __hip_bfloat162 p0 = __float22bfloat162_rn(make_float2(o0, o1));
            __hip_bfloat162 p1 = __float22bfloat162_rn(make_float2(o2, o3));
            __hip_bfloat162 p2 = __float22bfloat162_rn(make_float2(o4, o5));
            __hip_bfloat162 p3 = __float22bfloat162_rn(make_float2(o6, o7));
            uint4 w;
            w.x = *(u32*)&p0; w.y = *(u32*)&p1; w.z = *(u32*)&p2; w.w = *(u32*)&p3;
            *(uint4*)&g2[base] = w;
        }
    }
}

// ============ layer-2 gather pass: accumulates into hagg fp32 (in place) ====
__global__ __launch_bounds__(256) void k_g2pass(const int* __restrict__ rowptr4,
                                                const int* __restrict__ srcs,
                                                const float* __restrict__ dinv,
                                                const u16* __restrict__ g2,
                                                float* __restrict__ hagg, int n,
                                                int pass, int isFirst, int isLast) {
    const int* rp = rowptr4 + (size_t)pass * (n + 1);
    int tid = threadIdx.x;
    int r = tid >> 6, lane = tid & 63;
    int grp = lane >> 3, q = lane & 7;
    int i = blockIdx.x * 4 + r;
    if (i >= n) return;
    int beg = rp[i], end = rp[i + 1];
    float a[8];
#pragma unroll
    for (int k = 0; k < 8; k++) a[k] = 0.f;
    int j = beg + grp;
    for (; j + 8 < end; j += 16) {
        int s0 = __builtin_nontemporal_load(&srcs[j]);
        int s1 = __builtin_nontemporal_load(&srcs[j + 8]);
        uint4 u0 = *(const uint4*)&g2[(size_t)s0 * HDIM + q * 8];
        uint4 u1 = *(const uint4*)&g2[(size_t)s1 * HDIM + q * 8];
        a[0] += bflo(u0.x) + bflo(u1.x); a[1] += bfhi(u0.x) + bfhi(u1.x);
        a[2] += bflo(u0.y) + bflo(u1.y); a[3] += bfhi(u0.y) + bfhi(u1.y);
        a[4] += bflo(u0.z) + bflo(u1.z); a[5] += bfhi(u0.z) + bfhi(u1.z);
        a[6] += bflo(u0.w) + bflo(u1.w); a[7] += bfhi(u0.w) + bfhi(u1.w);
    }
    if (j < end) {
        int s0 = __builtin_nontemporal_load(&srcs[j]);
        uint4 u0 = *(const uint4*)&g2[(size_t)s0 * HDIM + q * 8];
        a[0] += bflo(u0.x); a[1] += bfhi(u0.x);
        a[2] += bflo(u0.y); a[3] += bfhi(u0.y);
        a[4] += bflo(u0.z); a[5] += bfhi(u0.z);
        a[6] += bflo(u0.w); a[7] += bfhi(u0.w);
    }
#pragma unroll
    for (int k = 0; k < 8; k++) {
        a[k] += __shfl_xor(a[k], 8);
        a[k] += __shfl_xor(a[k], 16);
        a[k] += __shfl_xor(a[k], 32);
    }
    if (grp == 0) {
        size_t base = (size_t)i * HDIM + q * 8;
        if (!isFirst) {
            f4 p0 = ntload4(&hagg[base]);
            f4 p1 = ntload4(&hagg[base + 4]);
            a[0] += p0[0]; a[1] += p0[1]; a[2] += p0[2]; a[3] += p0[3];
            a[4] += p1[0]; a[5] += p1[1]; a[6] += p1[2]; a[7] += p1[3];
        }
        if (!isLast) {
            f4 s0v = {a[0], a[1], a[2], a[3]};
            f4 s1v = {a[4], a[5], a[6], a[7]};
            ntstore4(&hagg[base], s0v);
            ntstore4(&hagg[base + 4], s1v);
        } else {
            uint4 us = *(const uint4*)&g2[base];   // self row
            float di = dinv[i];
            f4 o0, o1;
            o0[0] = di * (a[0] + bflo(us.x));
            o0[1] = di * (a[1] + bfhi(us.x));
            o0[2] = di * (a[2] + bflo(us.y));
            o0[3] = di * (a[3] + bfhi(us.y));
            o1[0] = di * (a[4] + bflo(us.z));
            o1[1] = di * (a[5] + bfhi(us.z));
            o1[2] = di * (a[6] + bflo(us.w));
            o1[3] = di * (a[7] + bfhi(us.w));
            ntstore4(&hagg[base], o0);
            ntstore4(&hagg[base + 4], o1);
        }
    }
}

// ============ GEMM2 (bf16 MFMA, split hi/lo) + epilogue ============
__global__ __launch_bounds__(256) void k_gemm2(const float* __restrict__ hagg,
                                               const short* __restrict__ Whi,
                                               const short* __restrict__ Wlo,
                                               const float* __restrict__ bmu,
                                               const float* __restrict__ bvar,
                                               const float* __restrict__ eps,
                                               float* __restrict__ out, int n) {
    int tid = threadIdx.x;
    int w = tid >> 6, lane = tid & 63;
    int m = lane & 15, kb = lane >> 4;
    int row0 = blockIdx.x * 128 + w * 32;

    short8 ah[2][2], al[2][2];
#pragma unroll
    for (int rb = 0; rb < 2; rb++) {
#pragma unroll
        for (int ks = 0; ks < 2; ks++) {
            int grow = row0 + rb * 16 + m;
            float v[8];
            if (grow < n) {
                const float* base = &hagg[(size_t)grow * HDIM + ks * 32 + kb * 8];
                float4 v0 = *(const float4*)base;
                float4 v1 = *(const float4*)(base + 4);
                v[0] = v0.x; v[1] = v0.y; v[2] = v0.z; v[3] = v0.w;
                v[4] = v1.x; v[5] = v1.y; v[6] = v1.z; v[7] = v1.w;
            } else {
#pragma unroll
                for (int jj = 0; jj < 8; jj++) v[jj] = 0.f;
            }
#pragma unroll
            for (int jj = 0; jj < 8; jj++) {
                __hip_bfloat16 h = __float2bfloat16(v[jj]);
                float hf = __bfloat162float(h);
                __hip_bfloat16 l = __float2bfloat16(v[jj] - hf);
                ah[rb][ks][jj] = *(short*)&h;
                al[rb][ks][jj] = *(short*)&l;
            }
        }
    }

    f32x4 acc[2][8];
#pragma unroll
    for (int rb = 0; rb < 2; rb++)
#pragma unroll
        for (int nt = 0; nt < 8; nt++) acc[rb][nt] = (f32x4){0.f, 0.f, 0.f, 0.f};

#pragma unroll
    for (int nt = 0; nt < 8; nt++) {
#pragma unroll
        for (int ks = 0; ks < 2; ks++) {
            const short* bbase = &Whi[(size_t)(nt * 16 + m) * HDIM + ks * 32 + kb * 8];
            const short* lbase = &Wlo[(size_t)(nt * 16 + m) * HDIM + ks * 32 + kb * 8];
            short8 bh = *(const short8*)bbase;
            short8 bl = *(const short8*)lbase;
#pragma unroll
            for (int rb = 0; rb < 2; rb++) {
                acc[rb][nt] = __builtin_amdgcn_mfma_f32_16x16x32_bf16(ah[rb][ks], bh, acc[rb][nt], 0, 0, 0);
                acc[rb][nt] = __builtin_amdgcn_mfma_f32_16x16x32_bf16(al[rb][ks], bh, acc[rb][nt], 0, 0, 0);
                acc[rb][nt] = __builtin_amdgcn_mfma_f32_16x16x32_bf16(ah[rb][ks], bl, acc[rb][nt], 0, 0, 0);
            }
        }
    }

    size_t nh = (size_t)n * HDIM;
#pragma unroll
    for (int rb = 0; rb < 2; rb++) {
#pragma unroll
        for (int nt = 0; nt < 4; nt++) {
            int c = nt * 16 + m;
            float bm = bmu[c], bv = bvar[c];
#pragma unroll
            for (int reg = 0; reg < 4; reg++) {
                int grow = row0 + rb * 16 + kb * 4 + reg;
                if (grow < n) {
                    float mu = acc[rb][nt][reg] + bm;
                    float va = acc[rb][nt + 4][reg] + bv;
                    float zv = fmaxf(va, 0.f) + log1pf(expf(-fabsf(va)));
                    size_t o = (size_t)grow * HDIM + c;
                    float z = mu + zv * eps[o];
                    out[o] = mu;
                    out[nh + o] = zv;
                    out[2 * nh + o] = z;
                }
            }
        }
    }
}

extern "C" void kernel_launch(void* const* d_in, const int* in_sizes, int n_in,
                              void* d_out, int out_size, void* d_ws, size_t ws_size,
                              hipStream_t stream) {
    const float* x    = (const float*)d_in[0];
    const int*   ei   = (const int*)d_in[1];
    const float* W1   = (const float*)d_in[2];
    const float* b1   = (const float*)d_in[3];
    const float* Wmu  = (const float*)d_in[4];
    const float* bmu  = (const float*)d_in[5];
    const float* Wvar = (const float*)d_in[6];
    const float* bvar = (const float*)d_in[7];
    const float* eps  = (const float*)d_in[8];
    float* out = (float*)d_out;

    int n = in_sizes[0] / IDIM;
    int E = in_sizes[1] / 2;
    const int* src = ei;
    const int* dst = ei + E;

    int NBd = (n + (1 << CB_SH) - 1) >> CB_SH;   // dst buckets (196)
    int NBK = NSB * NBd;                         // total keys (784 <= 1024)
    int Q   = (n + NSB - 1) / NSB;               // src slice width (25000)

    // workspace layout
    char* p = (char*)d_ws;
    u16* bufB   = (u16*)p;               p += (size_t)n * HDIM * 2;      // g2 table bf16
    float* hagg = (float*)p;             p += (size_t)n * HDIM * 4;      // slotA: hagg fp32
    u16* bufA   = (u16*)hagg;                                            //   alias: g1 table (dead before hagg written)
    int2* tmp   = (int2*)hagg;                                           //   alias: edge pairs (CSR phase)
    float* acc1 = (float*)p;             p += (size_t)n * HDIM * 4;      // layer-1 fp32 accumulator
    int* srcs   = (int*)p;               p += (size_t)E * 4;             // CSR cols
    short* Btg  = (short*)p;             p += (size_t)IDIM * HDIM * 2;   // W1^T bf16
    short* W2hi = (short*)p;             p += (size_t)128 * HDIM * 2;
    short* W2lo = (short*)p;             p += (size_t)128 * HDIM * 2;
    int* rowptr4 = (int*)p;              p += (size_t)NSB * (n + 1) * 4; // per-slice rowptrs
    float* dinv = (float*)p;             p += (size_t)n * 4;
    int* gHist  = (int*)p;               p += 1024 * 4;
    int* gcur   = (int*)p;               p += 1024 * 4;
    int* bucketBase = (int*)p;           p += 1025 * 4;

    // --- CSR build: (src-slice, dst-bucket) sort ---
    hipMemsetAsync(gHist, 0, (size_t)NBK * sizeof(int), stream);
    k_chist<<<512, 256, 0, stream>>>(src, dst, gHist, E, NBK, NBd, Q);
    k_cscan<<<1, 256, 0, stream>>>(gHist, bucketBase, gcur, NBK, NBd, rowptr4, n, E);
    k_partition<<<(E + PCHUNK - 1) / PCHUNK, 256, 0, stream>>>(src, dst, gcur, tmp, E, NBK, NBd, Q);
    k_finalize<<<NBK, 256, 0, stream>>>(tmp, bucketBase, rowptr4, srcs, n, NBd);
    k_dinv<<<(n + 255) / 256, 256, 0, stream>>>(rowptr4, dinv, n);

    // --- weight prep ---
    k_prepB<<<(IDIM * HDIM + 255) / 256, 256, 0, stream>>>(W1, Btg);
    k_prepW2<<<(128 * HDIM + 255) / 256, 256, 0, stream>>>(Wmu, Wvar, W2hi, W2lo);

    // --- layer 1 ---
    k_gemm1<<<(n + GM - 1) / GM, 256, 0, stream>>>(x, Btg, dinv, bufA, n);
    int gga = (n + 3) / 4;
    for (int sb = 0; sb < NSB; sb++)
        k_g1pass<<<gga, 256, 0, stream>>>(rowptr4, srcs, dinv, bufA, b1, acc1, bufB,
                                          n, sb, sb == 0, sb == NSB - 1);

    // --- layer 2: sliced aggregation into hagg, then MFMA epilogue GEMM ---
    for (int sb = 0; sb < NSB; sb++)
        k_g2pass<<<gga, 256, 0, stream>>>(rowptr4, srcs, dinv, bufB, hagg,
                                          n, sb, sb == 0, sb == NSB - 1);
    k_gemm2<<<(n + 127) / 128, 256, 0, stream>>>(hagg, W2hi, W2lo, bmu, bvar, eps, out, n);
}

// Round 5
// 614.914 us; speedup vs baseline: 1.2818x; 1.2818x over previous
//
#include <hip/hip_runtime.h>
#include <hip/hip_bf16.h>
#include <math.h>

#define IDIM 512
#define HDIM 64

// coarse bucketing for CSR build
#define CB_SH 9
#define CB_NODES 512          // 1 << CB_SH
#define PCHUNK 4096           // edges per partition block

typedef __attribute__((ext_vector_type(8))) short short8;   // 8 bf16 = 4 VGPRs
typedef __attribute__((ext_vector_type(4))) float f32x4;    // MFMA accum
typedef unsigned short u16;
typedef unsigned int u32;

__device__ __forceinline__ float bflo(u32 u) { return __uint_as_float(u << 16); }
__device__ __forceinline__ float bfhi(u32 u) { return __uint_as_float(u & 0xffff0000u); }

// ============ CSR build: coarse-bucket counting sort ============

__global__ __launch_bounds__(256) void k_chist(const int* __restrict__ dst,
                                               int* __restrict__ gHist, int E, int NB) {
    __shared__ int h[1024];
    int tid = threadIdx.x;
    for (int i = tid; i < NB; i += 256) h[i] = 0;
    __syncthreads();
    int stride = gridDim.x * 256;
    for (int e = blockIdx.x * 256 + tid; e < E; e += stride)
        atomicAdd(&h[dst[e] >> CB_SH], 1);
    __syncthreads();
    for (int i = tid; i < NB; i += 256)
        if (h[i]) atomicAdd(&gHist[i], h[i]);
}

__global__ __launch_bounds__(128) void k_cscan(const int* __restrict__ gHist,
                                               int* __restrict__ bucketBase,
                                               int* __restrict__ gcur, int NB,
                                               int* __restrict__ rowptr, int n, int E) {
    __shared__ int ss[128];
    int tid = threadIdx.x;
    int v[2];
    int s = 0;
#pragma unroll
    for (int k = 0; k < 2; k++) {
        int i = tid * 2 + k;
        v[k] = (i < NB) ? gHist[i] : 0;
        s += v[k];
    }
    ss[tid] = s;
    __syncthreads();
    for (int o = 1; o < 128; o <<= 1) {
        int u = (tid >= o) ? ss[tid - o] : 0;
        __syncthreads();
        ss[tid] += u;
        __syncthreads();
    }
    int ex = ss[tid] - s;
#pragma unroll
    for (int k = 0; k < 2; k++) {
        int i = tid * 2 + k;
        if (i < NB) { bucketBase[i] = ex; gcur[i] = ex; }
        ex += v[k];
    }
    if (tid == 0) { bucketBase[NB] = E; rowptr[n] = E; }
}

// partition edges into bucket-contiguous tmp; packed u32 = (src<<9)|(dst&511)
__global__ __launch_bounds__(256) void k_partition(const int* __restrict__ src,
                                                   const int* __restrict__ dst,
                                                   int* __restrict__ gcur,
                                                   u32* __restrict__ tmp, int E, int NB) {
    __shared__ int h[1024];
    __shared__ int base[1024];
    int tid = threadIdx.x;
    int e0 = blockIdx.x * PCHUNK;
    int e1 = min(e0 + PCHUNK, E);
    for (int i = tid; i < NB; i += 256) h[i] = 0;
    __syncthreads();
    for (int e = e0 + tid; e < e1; e += 256)
        atomicAdd(&h[dst[e] >> CB_SH], 1);
    __syncthreads();
    for (int i = tid; i < NB; i += 256) {
        int c = h[i];
        base[i] = c ? atomicAdd(&gcur[i], c) : 0;
        h[i] = 0;   // reuse as running cursor
    }
    __syncthreads();
    for (int e = e0 + tid; e < e1; e += 256) {
        int d = dst[e];
        int b = d >> CB_SH;
        int r = atomicAdd(&h[b], 1);
        tmp[base[b] + r] = ((u32)src[e] << CB_SH) | (u32)(d & (CB_NODES - 1));
    }
}

__global__ __launch_bounds__(256) void k_finalize(const u32* __restrict__ tmp,
                                                  const int* __restrict__ bucketBase,
                                                  int* __restrict__ rowptr,
                                                  float* __restrict__ dinv,
                                                  int* __restrict__ srcs, int n) {
    __shared__ int hist[CB_NODES];
    __shared__ int off[CB_NODES];
    __shared__ int ss[256];
    int b = blockIdx.x;
    int tid = threadIdx.x;
    int node0 = b << CB_SH;
    int nloc = min(CB_NODES, n - node0);
    int e0 = bucketBase[b], e1 = bucketBase[b + 1];
    hist[tid] = 0;
    hist[tid + 256] = 0;
    __syncthreads();
    for (int e = e0 + tid; e < e1; e += 256)
        atomicAdd(&hist[tmp[e] & (CB_NODES - 1)], 1);
    __syncthreads();
    int v0 = hist[2 * tid], v1 = hist[2 * tid + 1];
    int ps = v0 + v1;
    ss[tid] = ps;
    __syncthreads();
    for (int o = 1; o < 256; o <<= 1) {
        int u = (tid >= o) ? ss[tid - o] : 0;
        __syncthreads();
        ss[tid] += u;
        __syncthreads();
    }
    int ex = ss[tid] - ps;
    off[2 * tid] = ex;
    off[2 * tid + 1] = ex + v0;
    __syncthreads();
    for (int i = tid; i < nloc; i += 256) {
        rowptr[node0 + i] = e0 + off[i];
        dinv[node0 + i] = rsqrtf((float)hist[i] + 1.0f);
    }
    __syncthreads();
    for (int e = e0 + tid; e < e1; e += 256) {
        u32 p = tmp[e];
        int r = atomicAdd(&off[p & (CB_NODES - 1)], 1);
        srcs[e0 + r] = (int)(p >> CB_SH);
    }
}

// ============ W1 -> bf16 B^T table ============
__global__ __launch_bounds__(256) void k_prepB(const float* __restrict__ W1,
                                               short* __restrict__ Btg) {
    int id = blockIdx.x * 256 + threadIdx.x;
    if (id >= IDIM * HDIM) return;
    int k = id >> 6, nn = id & 63;
    __hip_bfloat16 b = __float2bfloat16(W1[id]);
    Btg[nn * IDIM + k] = *(short*)&b;
}

// ============ [Wmu|Wvar] -> bf16 hi/lo B^T tables [128 cols][64 k] ============
__global__ __launch_bounds__(256) void k_prepW2(const float* __restrict__ Wmu,
                                                const float* __restrict__ Wvar,
                                                short* __restrict__ Whi,
                                                short* __restrict__ Wlo) {
    int id = blockIdx.x * 256 + threadIdx.x;
    if (id >= 128 * 64) return;
    int c = id >> 6;
    int k = id & 63;
    float wv = (c < 64) ? Wmu[k * 64 + c] : Wvar[k * 64 + (c - 64)];
    __hip_bfloat16 h = __float2bfloat16(wv);
    float hf = __bfloat162float(h);
    __hip_bfloat16 l = __float2bfloat16(wv - hf);
    Whi[c * 64 + k] = *(short*)&h;
    Wlo[c * 64 + k] = *(short*)&l;
}

// ============ GEMM1 (bf16 MFMA): g1 = bf16((x @ W1) * dinv) ============
// KC=64 + register-prefetch pipeline: tile k+1's global loads are issued
// right after the barrier, BEFORE tile k's MFMA block, hiding HBM latency.
#define GM 128
#define KC 64
#define APAD 8
__global__ __launch_bounds__(256) void k_gemm1(const float* __restrict__ x,
                                               const short* __restrict__ Btg,
                                               const float* __restrict__ dinv,
                                               u16* __restrict__ g1, int n) {
    __shared__ short As[GM][KC + APAD];
    __shared__ short Bs[HDIM][KC + APAD];
    int tid = threadIdx.x;
    int row0 = blockIdx.x * GM;
    int w = tid >> 6, lane = tid & 63;
    int m = lane & 15, kb = lane >> 4;

    int ar = tid >> 4;          // A-stage row base: rows ar + i*16
    int ac4 = tid & 15;         // A-stage col chunk (4 floats)
    int br = tid >> 3;          // B-stage row base: rows br + i*32
    int bu8 = tid & 7;          // B-stage col chunk (8 bf16)

    f32x4 acc[2][4];
#pragma unroll
    for (int rb = 0; rb < 2; rb++)
#pragma unroll
        for (int nt = 0; nt < 4; nt++) acc[rb][nt] = (f32x4){0.f, 0.f, 0.f, 0.f};

    float4 pa[8];
    float4 pb[2];
    // preload tile kc=0
#pragma unroll
    for (int i = 0; i < 8; i++) {
        int grow = row0 + ar + i * 16;
        pa[i] = (grow < n) ? *(const float4*)&x[(size_t)grow * IDIM + ac4 * 4]
                           : make_float4(0.f, 0.f, 0.f, 0.f);
    }
#pragma unroll
    for (int i = 0; i < 2; i++)
        pb[i] = *(const float4*)&Btg[(size_t)(br + i * 32) * IDIM + bu8 * 8];

    for (int kc = 0; kc < IDIM; kc += KC) {
        // write staged registers into LDS
#pragma unroll
        for (int i = 0; i < 8; i++) {
            __hip_bfloat162 h0 = __float22bfloat162_rn(make_float2(pa[i].x, pa[i].y));
            __hip_bfloat162 h1 = __float22bfloat162_rn(make_float2(pa[i].z, pa[i].w));
            int2 pp;
            pp.x = *(int*)&h0;
            pp.y = *(int*)&h1;
            *(int2*)&As[ar + i * 16][ac4 * 4] = pp;
        }
#pragma unroll
        for (int i = 0; i < 2; i++)
            *(float4*)&Bs[br + i * 32][bu8 * 8] = pb[i];
        __syncthreads();

        // issue next tile's loads NOW (in flight across the MFMA block)
        if (kc + KC < IDIM) {
#pragma unroll
            for (int i = 0; i < 8; i++) {
                int grow = row0 + ar + i * 16;
                pa[i] = (grow < n) ? *(const float4*)&x[(size_t)grow * IDIM + kc + KC + ac4 * 4]
                                   : make_float4(0.f, 0.f, 0.f, 0.f);
            }
#pragma unroll
            for (int i = 0; i < 2; i++)
                pb[i] = *(const float4*)&Btg[(size_t)(br + i * 32) * IDIM + kc + KC + bu8 * 8];
        }

#pragma unroll
        for (int ks = 0; ks < KC; ks += 32) {
            short8 a0 = *(const short8*)&As[w * 32 + m][ks + kb * 8];
            short8 a1 = *(const short8*)&As[w * 32 + 16 + m][ks + kb * 8];
            short8 b0 = *(const short8*)&Bs[m][ks + kb * 8];
            short8 b1 = *(const short8*)&Bs[16 + m][ks + kb * 8];
            short8 b2 = *(const short8*)&Bs[32 + m][ks + kb * 8];
            short8 b3 = *(const short8*)&Bs[48 + m][ks + kb * 8];
            acc[0][0] = __builtin_amdgcn_mfma_f32_16x16x32_bf16(a0, b0, acc[0][0], 0, 0, 0);
            acc[0][1] = __builtin_amdgcn_mfma_f32_16x16x32_bf16(a0, b1, acc[0][1], 0, 0, 0);
            acc[0][2] = __builtin_amdgcn_mfma_f32_16x16x32_bf16(a0, b2, acc[0][2], 0, 0, 0);
            acc[0][3] = __builtin_amdgcn_mfma_f32_16x16x32_bf16(a0, b3, acc[0][3], 0, 0, 0);
            acc[1][0] = __builtin_amdgcn_mfma_f32_16x16x32_bf16(a1, b0, acc[1][0], 0, 0, 0);
            acc[1][1] = __builtin_amdgcn_mfma_f32_16x16x32_bf16(a1, b1, acc[1][1], 0, 0, 0);
            acc[1][2] = __builtin_amdgcn_mfma_f32_16x16x32_bf16(a1, b2, acc[1][2], 0, 0, 0);
            acc[1][3] = __builtin_amdgcn_mfma_f32_16x16x32_bf16(a1, b3, acc[1][3], 0, 0, 0);
        }
        __syncthreads();
    }
#pragma unroll
    for (int rb = 0; rb < 2; rb++) {
        int rbase = row0 + w * 32 + rb * 16 + kb * 4;
#pragma unroll
        for (int reg = 0; reg < 4; reg++) {
            int grow = rbase + reg;
            if (grow < n) {
                float dv = dinv[grow];
#pragma unroll
                for (int nt = 0; nt < 4; nt++) {
                    __hip_bfloat16 b = __float2bfloat16(acc[rb][nt][reg] * dv);
                    g1[(size_t)grow * HDIM + nt * 16 + m] = *(u16*)&b;
                }
            }
        }
    }
}

// ============ layer-1 gather (bf16 tables) ============
__global__ __launch_bounds__(256) void k_gather1(const int* __restrict__ rowptr,
                                                 const int* __restrict__ srcs,
                                                 const float* __restrict__ dinv,
                                                 const u16* __restrict__ g1,
                                                 const float* __restrict__ b1,
                                                 u16* __restrict__ g2, int n) {
    int tid = threadIdx.x;
    int r = tid >> 6, lane = tid & 63;
    int grp = lane >> 3, q = lane & 7;
    int i = blockIdx.x * 4 + r;
    if (i >= n) return;
    int beg = rowptr[i], end = rowptr[i + 1];
    float a[8];
#pragma unroll
    for (int k = 0; k < 8; k++) a[k] = 0.f;
    int j = beg + grp;
    for (; j + 8 < end; j += 16) {
        int s0 = srcs[j];
        int s1 = srcs[j + 8];
        uint4 u0 = *(const uint4*)&g1[(size_t)s0 * HDIM + q * 8];
        uint4 u1 = *(const uint4*)&g1[(size_t)s1 * HDIM + q * 8];
        a[0] += bflo(u0.x) + bflo(u1.x); a[1] += bfhi(u0.x) + bfhi(u1.x);
        a[2] += bflo(u0.y) + bflo(u1.y); a[3] += bfhi(u0.y) + bfhi(u1.y);
        a[4] += bflo(u0.z) + bflo(u1.z); a[5] += bfhi(u0.z) + bfhi(u1.z);
        a[6] += bflo(u0.w) + bflo(u1.w); a[7] += bfhi(u0.w) + bfhi(u1.w);
    }
    if (j < end) {
        int s0 = srcs[j];
        uint4 u0 = *(const uint4*)&g1[(size_t)s0 * HDIM + q * 8];
        a[0] += bflo(u0.x); a[1] += bfhi(u0.x);
        a[2] += bflo(u0.y); a[3] += bfhi(u0.y);
        a[4] += bflo(u0.z); a[5] += bfhi(u0.z);
        a[6] += bflo(u0.w); a[7] += bfhi(u0.w);
    }
#pragma unroll
    for (int k = 0; k < 8; k++) {
        a[k] += __shfl_xor(a[k], 8);
        a[k] += __shfl_xor(a[k], 16);
        a[k] += __shfl_xor(a[k], 32);
    }
    if (grp == 0) {
        uint4 us = *(const uint4*)&g1[(size_t)i * HDIM + q * 8];
        float s0 = bflo(us.x), s1 = bfhi(us.x), s2 = bflo(us.y), s3 = bfhi(us.y);
        float s4 = bflo(us.z), s5 = bfhi(us.z), s6 = bflo(us.w), s7 = bfhi(us.w);
        float4 bv0 = *(const float4*)&b1[q * 8];
        float4 bv1 = *(const float4*)&b1[q * 8 + 4];
        float di = dinv[i];
        float o0 = fmaxf(di * (a[0] + s0) + bv0.x, 0.f) * di;
        float o1 = fmaxf(di * (a[1] + s1) + bv0.y, 0.f) * di;
        float o2 = fmaxf(di * (a[2] + s2) + bv0.z, 0.f) * di;
        float o3 = fmaxf(di * (a[3] + s3) + bv0.w, 0.f) * di;
        float o4 = fmaxf(di * (a[4] + s4) + bv1.x, 0.f) * di;
        float o5 = fmaxf(di * (a[5] + s5) + bv1.y, 0.f) * di;
        float o6 = fmaxf(di * (a[6] + s6) + bv1.z, 0.f) * di;
        float o7 = fmaxf(di * (a[7] + s7) + bv1.w, 0.f) * di;
        __hip_bfloat162 p0 = __float22bfloat162_rn(make_float2(o0, o1));
        __hip_bfloat162 p1 = __float22bfloat162_rn(make_float2(o2, o3));
        __hip_bfloat162 p2 = __float22bfloat162_rn(make_float2(o4, o5));
        __hip_bfloat162 p3 = __float22bfloat162_rn(make_float2(o6, o7));
        uint4 w;
        w.x = *(u32*)&p0; w.y = *(u32*)&p1; w.z = *(u32*)&p2; w.w = *(u32*)&p3;
        *(uint4*)&g2[(size_t)i * HDIM + q * 8] = w;
    }
}

// ============ layer-2 gather: pure aggregation, writes h_agg fp32 ============
__global__ __launch_bounds__(256) void k_gather2(const int* __restrict__ rowptr,
                                                 const int* __restrict__ srcs,
                                                 const float* __restrict__ dinv,
                                                 const u16* __restrict__ g2,
                                                 float* __restrict__ hagg, int n) {
    int tid = threadIdx.x;
    int r = tid >> 6, lane = tid & 63;
    int grp = lane >> 3, q = lane & 7;
    int i = blockIdx.x * 4 + r;
    if (i >= n) return;
    int beg = rowptr[i], end = rowptr[i + 1];
    float a[8];
#pragma unroll
    for (int k = 0; k < 8; k++) a[k] = 0.f;
    int j = beg + grp;
    for (; j + 8 < end; j += 16) {
        int s0 = srcs[j];
        int s1 = srcs[j + 8];
        uint4 u0 = *(const uint4*)&g2[(size_t)s0 * HDIM + q * 8];
        uint4 u1 = *(const uint4*)&g2[(size_t)s1 * HDIM + q * 8];
        a[0] += bflo(u0.x) + bflo(u1.x); a[1] += bfhi(u0.x) + bfhi(u1.x);
        a[2] += bflo(u0.y) + bflo(u1.y); a[3] += bfhi(u0.y) + bfhi(u1.y);
        a[4] += bflo(u0.z) + bflo(u1.z); a[5] += bfhi(u0.z) + bfhi(u1.z);
        a[6] += bflo(u0.w) + bflo(u1.w); a[7] += bfhi(u0.w) + bfhi(u1.w);
    }
    if (j < end) {
        int s0 = srcs[j];
        uint4 u0 = *(const uint4*)&g2[(size_t)s0 * HDIM + q * 8];
        a[0] += bflo(u0.x); a[1] += bfhi(u0.x);
        a[2] += bflo(u0.y); a[3] += bfhi(u0.y);
        a[4] += bflo(u0.z); a[5] += bfhi(u0.z);
        a[6] += bflo(u0.w); a[7] += bfhi(u0.w);
    }
#pragma unroll
    for (int k = 0; k < 8; k++) {
        a[k] += __shfl_xor(a[k], 8);
        a[k] += __shfl_xor(a[k], 16);
        a[k] += __shfl_xor(a[k], 32);
    }
    if (grp == 0) {
        uint4 us = *(const uint4*)&g2[(size_t)i * HDIM + q * 8];
        float di = dinv[i];
        float4 o0, o1;
        o0.x = di * (a[0] + bflo(us.x));
        o0.y = di * (a[1] + bfhi(us.x));
        o0.z = di * (a[2] + bflo(us.y));
        o0.w = di * (a[3] + bfhi(us.y));
        o1.x = di * (a[4] + bflo(us.z));
        o1.y = di * (a[5] + bfhi(us.z));
        o1.z = di * (a[6] + bflo(us.w));
        o1.w = di * (a[7] + bfhi(us.w));
        *(float4*)&hagg[(size_t)i * HDIM + q * 8] = o0;
        *(float4*)&hagg[(size_t)i * HDIM + q * 8 + 4] = o1;
    }
}

// ============ GEMM2 (bf16 MFMA, split hi/lo) + epilogue ============
__global__ __launch_bounds__(256) void k_gemm2(const float* __restrict__ hagg,
                                               const short* __restrict__ Whi,
                                               const short* __restrict__ Wlo,
                                               const float* __restrict__ bmu,
                                               const float* __restrict__ bvar,
                                               const float* __restrict__ eps,
                                               float* __restrict__ out, int n) {
    int tid = threadIdx.x;
    int w = tid >> 6, lane = tid & 63;
    int m = lane & 15, kb = lane >> 4;
    int row0 = blockIdx.x * 128 + w * 32;

    short8 ah[2][2], al[2][2];
#pragma unroll
    for (int rb = 0; rb < 2; rb++) {
#pragma unroll
        for (int ks = 0; ks < 2; ks++) {
            int grow = row0 + rb * 16 + m;
            float v[8];
            if (grow < n) {
                const float* base = &hagg[(size_t)grow * HDIM + ks * 32 + kb * 8];
                float4 v0 = *(const float4*)base;
                float4 v1 = *(const float4*)(base + 4);
                v[0] = v0.x; v[1] = v0.y; v[2] = v0.z; v[3] = v0.w;
                v[4] = v1.x; v[5] = v1.y; v[6] = v1.z; v[7] = v1.w;
            } else {
#pragma unroll
                for (int jj = 0; jj < 8; jj++) v[jj] = 0.f;
            }
#pragma unroll
            for (int jj = 0; jj < 8; jj++) {
                __hip_bfloat16 h = __float2bfloat16(v[jj]);
                float hf = __bfloat162float(h);
                __hip_bfloat16 l = __float2bfloat16(v[jj] - hf);
                ah[rb][ks][jj] = *(short*)&h;
                al[rb][ks][jj] = *(short*)&l;
            }
        }
    }

    f32x4 acc[2][8];
#pragma unroll
    for (int rb = 0; rb < 2; rb++)
#pragma unroll
        for (int nt = 0; nt < 8; nt++) acc[rb][nt] = (f32x4){0.f, 0.f, 0.f, 0.f};

#pragma unroll
    for (int nt = 0; nt < 8; nt++) {
#pragma unroll
        for (int ks = 0; ks < 2; ks++) {
            const short* bbase = &Whi[(size_t)(nt * 16 + m) * HDIM + ks * 32 + kb * 8];
            const short* lbase = &Wlo[(size_t)(nt * 16 + m) * HDIM + ks * 32 + kb * 8];
            short8 bh = *(const short8*)bbase;
            short8 bl = *(const short8*)lbase;
#pragma unroll
            for (int rb = 0; rb < 2; rb++) {
                acc[rb][nt] = __builtin_amdgcn_mfma_f32_16x16x32_bf16(ah[rb][ks], bh, acc[rb][nt], 0, 0, 0);
                acc[rb][nt] = __builtin_amdgcn_mfma_f32_16x16x32_bf16(al[rb][ks], bh, acc[rb][nt], 0, 0, 0);
                acc[rb][nt] = __builtin_amdgcn_mfma_f32_16x16x32_bf16(ah[rb][ks], bl, acc[rb][nt], 0, 0, 0);
            }
        }
    }

    size_t nh = (size_t)n * HDIM;
#pragma unroll
    for (int rb = 0; rb < 2; rb++) {
#pragma unroll
        for (int nt = 0; nt < 4; nt++) {
            int c = nt * 16 + m;
            float bm = bmu[c], bv = bvar[c];
#pragma unroll
            for (int reg = 0; reg < 4; reg++) {
                int grow = row0 + rb * 16 + kb * 4 + reg;
                if (grow < n) {
                    float mu = acc[rb][nt][reg] + bm;
                    float va = acc[rb][nt + 4][reg] + bv;
                    float zv = fmaxf(va, 0.f) + log1pf(expf(-fabsf(va)));
                    size_t o = (size_t)grow * HDIM + c;
                    float z = mu + zv * eps[o];
                    out[o] = mu;
                    out[nh + o] = zv;
                    out[2 * nh + o] = z;
                }
            }
        }
    }
}

extern "C" void kernel_launch(void* const* d_in, const int* in_sizes, int n_in,
                              void* d_out, int out_size, void* d_ws, size_t ws_size,
                              hipStream_t stream) {
    const float* x    = (const float*)d_in[0];
    const int*   ei   = (const int*)d_in[1];
    const float* W1   = (const float*)d_in[2];
    const float* b1   = (const float*)d_in[3];
    const float* Wmu  = (const float*)d_in[4];
    const float* bmu  = (const float*)d_in[5];
    const float* Wvar = (const float*)d_in[6];
    const float* bvar = (const float*)d_in[7];
    const float* eps  = (const float*)d_in[8];
    float* out = (float*)d_out;

    int n = in_sizes[0] / IDIM;
    int E = in_sizes[1] / 2;
    const int* src = ei;
    const int* dst = ei + E;

    int NB = (n + CB_NODES - 1) >> CB_SH;

    // workspace layout
    char* p = (char*)d_ws;
    u16* bufB   = (u16*)p;               p += (size_t)n * HDIM * 2;      // g2 bf16
    float* hagg = (float*)p;             p += (size_t)n * HDIM * 4;      // hagg fp32
    u16* bufA   = (u16*)hagg;                                            //   alias: g1 bf16
    u32* tmp    = (u32*)hagg;                                            //   alias: packed edges (CSR phase)
    int* srcs   = (int*)p;               p += (size_t)E * 4;             // CSR cols
    short* Btg  = (short*)p;             p += (size_t)IDIM * HDIM * 2;   // W1^T bf16
    short* W2hi = (short*)p;             p += (size_t)128 * HDIM * 2;
    short* W2lo = (short*)p;             p += (size_t)128 * HDIM * 2;
    int* rowptr = (int*)p;               p += (size_t)(n + 1) * 4;
    float* dinv = (float*)p;             p += (size_t)n * 4;
    int* gHist  = (int*)p;               p += 1024 * 4;
    int* gcur   = (int*)p;               p += 1024 * 4;
    int* bucketBase = (int*)p;           p += 1025 * 4;

    // --- CSR build (bucketed counting sort; tmp aliases hagg, dead before gemm1) ---
    hipMemsetAsync(gHist, 0, (size_t)NB * sizeof(int), stream);
    k_chist<<<512, 256, 0, stream>>>(dst, gHist, E, NB);
    k_cscan<<<1, 128, 0, stream>>>(gHist, bucketBase, gcur, NB, rowptr, n, E);
    k_partition<<<(E + PCHUNK - 1) / PCHUNK, 256, 0, stream>>>(src, dst, gcur, tmp, E, NB);
    k_finalize<<<NB, 256, 0, stream>>>(tmp, bucketBase, rowptr, dinv, srcs, n);

    // --- weight prep ---
    k_prepB<<<(IDIM * HDIM + 255) / 256, 256, 0, stream>>>(W1, Btg);
    k_prepW2<<<(128 * HDIM + 255) / 256, 256, 0, stream>>>(Wmu, Wvar, W2hi, W2lo);

    // --- layer 1 ---
    k_gemm1<<<(n + GM - 1) / GM, 256, 0, stream>>>(x, Btg, dinv, bufA, n);
    k_gather1<<<(n + 3) / 4, 256, 0, stream>>>(rowptr, srcs, dinv, bufA, b1, bufB, n);

    // --- layer 2: aggregate, then MFMA epilogue GEMM ---
    k_gather2<<<(n + 3) / 4, 256, 0, stream>>>(rowptr, srcs, dinv, bufB, hagg, n);
    k_gemm2<<<(n + 127) / 128, 256, 0, stream>>>(hagg, W2hi, W2lo, bmu, bvar, eps, out, n);
}

// Round 6
// 582.907 us; speedup vs baseline: 1.3522x; 1.0549x over previous
//
#include <hip/hip_runtime.h>
#include <hip/hip_bf16.h>
#include <math.h>

#define IDIM 512
#define HDIM 64

// coarse bucketing for CSR build
#define CB_SH 9
#define CB_NODES 512          // 1 << CB_SH
#define PCHUNK 4096           // edges per partition block

typedef __attribute__((ext_vector_type(8))) short short8;   // 8 bf16 = 4 VGPRs
typedef __attribute__((ext_vector_type(4))) float f32x4;    // MFMA accum
typedef unsigned short u16;
typedef unsigned int u32;

__device__ __forceinline__ float bflo(u32 u) { return __uint_as_float(u << 16); }
__device__ __forceinline__ float bfhi(u32 u) { return __uint_as_float(u & 0xffff0000u); }

// ============ CSR build: coarse-bucket counting sort ============

__global__ __launch_bounds__(256) void k_chist(const int* __restrict__ dst,
                                               int* __restrict__ gHist, int E, int NB) {
    __shared__ int h[1024];
    int tid = threadIdx.x;
    for (int i = tid; i < NB; i += 256) h[i] = 0;
    __syncthreads();
    int stride = gridDim.x * 256;
    for (int e = blockIdx.x * 256 + tid; e < E; e += stride)
        atomicAdd(&h[dst[e] >> CB_SH], 1);
    __syncthreads();
    for (int i = tid; i < NB; i += 256)
        if (h[i]) atomicAdd(&gHist[i], h[i]);
}

__global__ __launch_bounds__(128) void k_cscan(const int* __restrict__ gHist,
                                               int* __restrict__ bucketBase,
                                               int* __restrict__ gcur, int NB,
                                               int* __restrict__ rowptr, int n, int E) {
    __shared__ int ss[128];
    int tid = threadIdx.x;
    int v[2];
    int s = 0;
#pragma unroll
    for (int k = 0; k < 2; k++) {
        int i = tid * 2 + k;
        v[k] = (i < NB) ? gHist[i] : 0;
        s += v[k];
    }
    ss[tid] = s;
    __syncthreads();
    for (int o = 1; o < 128; o <<= 1) {
        int u = (tid >= o) ? ss[tid - o] : 0;
        __syncthreads();
        ss[tid] += u;
        __syncthreads();
    }
    int ex = ss[tid] - s;
#pragma unroll
    for (int k = 0; k < 2; k++) {
        int i = tid * 2 + k;
        if (i < NB) { bucketBase[i] = ex; gcur[i] = ex; }
        ex += v[k];
    }
    if (tid == 0) { bucketBase[NB] = E; rowptr[n] = E; }
}

// partition edges into bucket-contiguous tmp; packed u32 = (src<<9)|(dst&511)
__global__ __launch_bounds__(256) void k_partition(const int* __restrict__ src,
                                                   const int* __restrict__ dst,
                                                   int* __restrict__ gcur,
                                                   u32* __restrict__ tmp, int E, int NB) {
    __shared__ int h[1024];
    __shared__ int base[1024];
    int tid = threadIdx.x;
    int e0 = blockIdx.x * PCHUNK;
    int e1 = min(e0 + PCHUNK, E);
    for (int i = tid; i < NB; i += 256) h[i] = 0;
    __syncthreads();
    for (int e = e0 + tid; e < e1; e += 256)
        atomicAdd(&h[dst[e] >> CB_SH], 1);
    __syncthreads();
    for (int i = tid; i < NB; i += 256) {
        int c = h[i];
        base[i] = c ? atomicAdd(&gcur[i], c) : 0;
        h[i] = 0;   // reuse as running cursor
    }
    __syncthreads();
    for (int e = e0 + tid; e < e1; e += 256) {
        int d = dst[e];
        int b = d >> CB_SH;
        int r = atomicAdd(&h[b], 1);
        tmp[base[b] + r] = ((u32)src[e] << CB_SH) | (u32)(d & (CB_NODES - 1));
    }
}

__global__ __launch_bounds__(256) void k_finalize(const u32* __restrict__ tmp,
                                                  const int* __restrict__ bucketBase,
                                                  int* __restrict__ rowptr,
                                                  float* __restrict__ dinv,
                                                  int* __restrict__ srcs, int n) {
    __shared__ int hist[CB_NODES];
    __shared__ int off[CB_NODES];
    __shared__ int ss[256];
    int b = blockIdx.x;
    int tid = threadIdx.x;
    int node0 = b << CB_SH;
    int nloc = min(CB_NODES, n - node0);
    int e0 = bucketBase[b], e1 = bucketBase[b + 1];
    hist[tid] = 0;
    hist[tid + 256] = 0;
    __syncthreads();
    for (int e = e0 + tid; e < e1; e += 256)
        atomicAdd(&hist[tmp[e] & (CB_NODES - 1)], 1);
    __syncthreads();
    int v0 = hist[2 * tid], v1 = hist[2 * tid + 1];
    int ps = v0 + v1;
    ss[tid] = ps;
    __syncthreads();
    for (int o = 1; o < 256; o <<= 1) {
        int u = (tid >= o) ? ss[tid - o] : 0;
        __syncthreads();
        ss[tid] += u;
        __syncthreads();
    }
    int ex = ss[tid] - ps;
    off[2 * tid] = ex;
    off[2 * tid + 1] = ex + v0;
    __syncthreads();
    for (int i = tid; i < nloc; i += 256) {
        rowptr[node0 + i] = e0 + off[i];
        dinv[node0 + i] = rsqrtf((float)hist[i] + 1.0f);
    }
    __syncthreads();
    for (int e = e0 + tid; e < e1; e += 256) {
        u32 p = tmp[e];
        int r = atomicAdd(&off[p & (CB_NODES - 1)], 1);
        srcs[e0 + r] = (int)(p >> CB_SH);
    }
}

// ============ W1 -> bf16 B^T table ============
__global__ __launch_bounds__(256) void k_prepB(const float* __restrict__ W1,
                                               short* __restrict__ Btg) {
    int id = blockIdx.x * 256 + threadIdx.x;
    if (id >= IDIM * HDIM) return;
    int k = id >> 6, nn = id & 63;
    __hip_bfloat16 b = __float2bfloat16(W1[id]);
    Btg[nn * IDIM + k] = *(short*)&b;
}

// ============ [Wmu|Wvar] -> bf16 hi/lo B^T tables [128 cols][64 k] ============
__global__ __launch_bounds__(256) void k_prepW2(const float* __restrict__ Wmu,
                                                const float* __restrict__ Wvar,
                                                short* __restrict__ Whi,
                                                short* __restrict__ Wlo) {
    int id = blockIdx.x * 256 + threadIdx.x;
    if (id >= 128 * 64) return;
    int c = id >> 6;
    int k = id & 63;
    float wv = (c < 64) ? Wmu[k * 64 + c] : Wvar[k * 64 + (c - 64)];
    __hip_bfloat16 h = __float2bfloat16(wv);
    float hf = __bfloat162float(h);
    __hip_bfloat16 l = __float2bfloat16(wv - hf);
    Whi[c * 64 + k] = *(short*)&h;
    Wlo[c * 64 + k] = *(short*)&l;
}

// ============ GEMM1 (bf16 MFMA): g1 = bf16((x @ W1) * dinv) ============
// GM=64: grid 1563 (~6 blocks/CU) fixes grid-starvation (R5: 782 blocks, 23% occ).
// Coalesced C-write through LDS kills the 4.7x write-allocate amplification.
#define GM 64
#define KC 64
#define APAD 8
__global__ __launch_bounds__(256) void k_gemm1(const float* __restrict__ x,
                                               const short* __restrict__ Btg,
                                               const float* __restrict__ dinv,
                                               u16* __restrict__ g1, int n) {
    __shared__ short As[GM][KC + APAD];
    __shared__ short Bs[HDIM][KC + APAD];
    int tid = threadIdx.x;
    int row0 = blockIdx.x * GM;
    int w = tid >> 6, lane = tid & 63;
    int m = lane & 15, kb = lane >> 4;

    int ar = tid >> 4;          // A-stage row: ar + i*16
    int ac4 = tid & 15;         // A-stage col chunk (4 floats)
    int br = tid >> 3;          // B-stage row: br + i*32
    int bu8 = tid & 7;          // B-stage col chunk (8 bf16)

    f32x4 acc[4];
#pragma unroll
    for (int nt = 0; nt < 4; nt++) acc[nt] = (f32x4){0.f, 0.f, 0.f, 0.f};

    float4 pa[4];
    float4 pb[2];
    // preload tile kc=0
#pragma unroll
    for (int i = 0; i < 4; i++) {
        int grow = row0 + ar + i * 16;
        pa[i] = (grow < n) ? *(const float4*)&x[(size_t)grow * IDIM + ac4 * 4]
                           : make_float4(0.f, 0.f, 0.f, 0.f);
    }
#pragma unroll
    for (int i = 0; i < 2; i++)
        pb[i] = *(const float4*)&Btg[(size_t)(br + i * 32) * IDIM + bu8 * 8];

    for (int kc = 0; kc < IDIM; kc += KC) {
#pragma unroll
        for (int i = 0; i < 4; i++) {
            __hip_bfloat162 h0 = __float22bfloat162_rn(make_float2(pa[i].x, pa[i].y));
            __hip_bfloat162 h1 = __float22bfloat162_rn(make_float2(pa[i].z, pa[i].w));
            int2 pp;
            pp.x = *(int*)&h0;
            pp.y = *(int*)&h1;
            *(int2*)&As[ar + i * 16][ac4 * 4] = pp;
        }
#pragma unroll
        for (int i = 0; i < 2; i++)
            *(float4*)&Bs[br + i * 32][bu8 * 8] = pb[i];
        __syncthreads();

        // issue next tile's loads NOW (in flight across MFMA + other waves)
        if (kc + KC < IDIM) {
#pragma unroll
            for (int i = 0; i < 4; i++) {
                int grow = row0 + ar + i * 16;
                pa[i] = (grow < n) ? *(const float4*)&x[(size_t)grow * IDIM + kc + KC + ac4 * 4]
                                   : make_float4(0.f, 0.f, 0.f, 0.f);
            }
#pragma unroll
            for (int i = 0; i < 2; i++)
                pb[i] = *(const float4*)&Btg[(size_t)(br + i * 32) * IDIM + kc + KC + bu8 * 8];
        }

#pragma unroll
        for (int ks = 0; ks < KC; ks += 32) {
            short8 a0 = *(const short8*)&As[w * 16 + m][ks + kb * 8];
            short8 b0 = *(const short8*)&Bs[m][ks + kb * 8];
            short8 b1 = *(const short8*)&Bs[16 + m][ks + kb * 8];
            short8 b2 = *(const short8*)&Bs[32 + m][ks + kb * 8];
            short8 b3 = *(const short8*)&Bs[48 + m][ks + kb * 8];
            acc[0] = __builtin_amdgcn_mfma_f32_16x16x32_bf16(a0, b0, acc[0], 0, 0, 0);
            acc[1] = __builtin_amdgcn_mfma_f32_16x16x32_bf16(a0, b1, acc[1], 0, 0, 0);
            acc[2] = __builtin_amdgcn_mfma_f32_16x16x32_bf16(a0, b2, acc[2], 0, 0, 0);
            acc[3] = __builtin_amdgcn_mfma_f32_16x16x32_bf16(a0, b3, acc[3], 0, 0, 0);
        }
        __syncthreads();
    }

    // ---- coalesced epilogue: stage bf16 C-tile in LDS (reuse As), then
    // write 64 rows x 128B with full-line stores ----
    u16* Cs = (u16*)&As[0][0];          // [64][64] u16, stride 64
#pragma unroll
    for (int reg = 0; reg < 4; reg++) {
        int lrow = w * 16 + kb * 4 + reg;
        int grow = row0 + lrow;
        float dv = (grow < n) ? dinv[grow] : 0.f;
#pragma unroll
        for (int nt = 0; nt < 4; nt++) {
            __hip_bfloat16 b = __float2bfloat16(acc[nt][reg] * dv);
            Cs[lrow * 64 + nt * 16 + m] = *(u16*)&b;
        }
    }
    __syncthreads();
    {
        int lrow = tid >> 2;            // 4 threads per row
        int ch = tid & 3;               // 32B chunk within the 128B row
        int grow = row0 + lrow;
        if (grow < n) {
            uint4 v0 = *(const uint4*)&Cs[lrow * 64 + ch * 16];
            uint4 v1 = *(const uint4*)&Cs[lrow * 64 + ch * 16 + 8];
            *(uint4*)&g1[(size_t)grow * HDIM + ch * 16] = v0;
            *(uint4*)&g1[(size_t)grow * HDIM + ch * 16 + 8] = v1;
        }
    }
}

// ============ layer-1 gather (bf16 tables) ============
__global__ __launch_bounds__(256) void k_gather1(const int* __restrict__ rowptr,
                                                 const int* __restrict__ srcs,
                                                 const float* __restrict__ dinv,
                                                 const u16* __restrict__ g1,
                                                 const float* __restrict__ b1,
                                                 u16* __restrict__ g2, int n) {
    int tid = threadIdx.x;
    int r = tid >> 6, lane = tid & 63;
    int grp = lane >> 3, q = lane & 7;
    int i = blockIdx.x * 4 + r;
    if (i >= n) return;
    int beg = rowptr[i], end = rowptr[i + 1];
    float a[8];
#pragma unroll
    for (int k = 0; k < 8; k++) a[k] = 0.f;
    int j = beg + grp;
    for (; j + 8 < end; j += 16) {
        int s0 = srcs[j];
        int s1 = srcs[j + 8];
        uint4 u0 = *(const uint4*)&g1[(size_t)s0 * HDIM + q * 8];
        uint4 u1 = *(const uint4*)&g1[(size_t)s1 * HDIM + q * 8];
        a[0] += bflo(u0.x) + bflo(u1.x); a[1] += bfhi(u0.x) + bfhi(u1.x);
        a[2] += bflo(u0.y) + bflo(u1.y); a[3] += bfhi(u0.y) + bfhi(u1.y);
        a[4] += bflo(u0.z) + bflo(u1.z); a[5] += bfhi(u0.z) + bfhi(u1.z);
        a[6] += bflo(u0.w) + bflo(u1.w); a[7] += bfhi(u0.w) + bfhi(u1.w);
    }
    if (j < end) {
        int s0 = srcs[j];
        uint4 u0 = *(const uint4*)&g1[(size_t)s0 * HDIM + q * 8];
        a[0] += bflo(u0.x); a[1] += bfhi(u0.x);
        a[2] += bflo(u0.y); a[3] += bfhi(u0.y);
        a[4] += bflo(u0.z); a[5] += bfhi(u0.z);
        a[6] += bflo(u0.w); a[7] += bfhi(u0.w);
    }
#pragma unroll
    for (int k = 0; k < 8; k++) {
        a[k] += __shfl_xor(a[k], 8);
        a[k] += __shfl_xor(a[k], 16);
        a[k] += __shfl_xor(a[k], 32);
    }
    if (grp == 0) {
        uint4 us = *(const uint4*)&g1[(size_t)i * HDIM + q * 8];
        float s0 = bflo(us.x), s1 = bfhi(us.x), s2 = bflo(us.y), s3 = bfhi(us.y);
        float s4 = bflo(us.z), s5 = bfhi(us.z), s6 = bflo(us.w), s7 = bfhi(us.w);
        float4 bv0 = *(const float4*)&b1[q * 8];
        float4 bv1 = *(const float4*)&b1[q * 8 + 4];
        float di = dinv[i];
        float o0 = fmaxf(di * (a[0] + s0) + bv0.x, 0.f) * di;
        float o1 = fmaxf(di * (a[1] + s1) + bv0.y, 0.f) * di;
        float o2 = fmaxf(di * (a[2] + s2) + bv0.z, 0.f) * di;
        float o3 = fmaxf(di * (a[3] + s3) + bv0.w, 0.f) * di;
        float o4 = fmaxf(di * (a[4] + s4) + bv1.x, 0.f) * di;
        float o5 = fmaxf(di * (a[5] + s5) + bv1.y, 0.f) * di;
        float o6 = fmaxf(di * (a[6] + s6) + bv1.z, 0.f) * di;
        float o7 = fmaxf(di * (a[7] + s7) + bv1.w, 0.f) * di;
        __hip_bfloat162 p0 = __float22bfloat162_rn(make_float2(o0, o1));
        __hip_bfloat162 p1 = __float22bfloat162_rn(make_float2(o2, o3));
        __hip_bfloat162 p2 = __float22bfloat162_rn(make_float2(o4, o5));
        __hip_bfloat162 p3 = __float22bfloat162_rn(make_float2(o6, o7));
        uint4 w;
        w.x = *(u32*)&p0; w.y = *(u32*)&p1; w.z = *(u32*)&p2; w.w = *(u32*)&p3;
        *(uint4*)&g2[(size_t)i * HDIM + q * 8] = w;
    }
}

// ============ layer-2 gather: pure aggregation, writes h_agg fp32 ============
__global__ __launch_bounds__(256) void k_gather2(const int* __restrict__ rowptr,
                                                 const int* __restrict__ srcs,
                                                 const float* __restrict__ dinv,
                                                 const u16* __restrict__ g2,
                                                 float* __restrict__ hagg, int n) {
    int tid = threadIdx.x;
    int r = tid >> 6, lane = tid & 63;
    int grp = lane >> 3, q = lane & 7;
    int i = blockIdx.x * 4 + r;
    if (i >= n) return;
    int beg = rowptr[i], end = rowptr[i + 1];
    float a[8];
#pragma unroll
    for (int k = 0; k < 8; k++) a[k] = 0.f;
    int j = beg + grp;
    for (; j + 8 < end; j += 16) {
        int s0 = srcs[j];
        int s1 = srcs[j + 8];
        uint4 u0 = *(const uint4*)&g2[(size_t)s0 * HDIM + q * 8];
        uint4 u1 = *(const uint4*)&g2[(size_t)s1 * HDIM + q * 8];
        a[0] += bflo(u0.x) + bflo(u1.x); a[1] += bfhi(u0.x) + bfhi(u1.x);
        a[2] += bflo(u0.y) + bflo(u1.y); a[3] += bfhi(u0.y) + bfhi(u1.y);
        a[4] += bflo(u0.z) + bflo(u1.z); a[5] += bfhi(u0.z) + bfhi(u1.z);
        a[6] += bflo(u0.w) + bflo(u1.w); a[7] += bfhi(u0.w) + bfhi(u1.w);
    }
    if (j < end) {
        int s0 = srcs[j];
        uint4 u0 = *(const uint4*)&g2[(size_t)s0 * HDIM + q * 8];
        a[0] += bflo(u0.x); a[1] += bfhi(u0.x);
        a[2] += bflo(u0.y); a[3] += bfhi(u0.y);
        a[4] += bflo(u0.z); a[5] += bfhi(u0.z);
        a[6] += bflo(u0.w); a[7] += bfhi(u0.w);
    }
#pragma unroll
    for (int k = 0; k < 8; k++) {
        a[k] += __shfl_xor(a[k], 8);
        a[k] += __shfl_xor(a[k], 16);
        a[k] += __shfl_xor(a[k], 32);
    }
    if (grp == 0) {
        uint4 us = *(const uint4*)&g2[(size_t)i * HDIM + q * 8];
        float di = dinv[i];
        float4 o0, o1;
        o0.x = di * (a[0] + bflo(us.x));
        o0.y = di * (a[1] + bfhi(us.x));
        o0.z = di * (a[2] + bflo(us.y));
        o0.w = di * (a[3] + bfhi(us.y));
        o1.x = di * (a[4] + bflo(us.z));
        o1.y = di * (a[5] + bfhi(us.z));
        o1.z = di * (a[6] + bflo(us.w));
        o1.w = di * (a[7] + bfhi(us.w));
        *(float4*)&hagg[(size_t)i * HDIM + q * 8] = o0;
        *(float4*)&hagg[(size_t)i * HDIM + q * 8 + 4] = o1;
    }
}

// ============ GEMM2 (bf16 MFMA, split hi/lo) + epilogue ============
__global__ __launch_bounds__(256) void k_gemm2(const float* __restrict__ hagg,
                                               const short* __restrict__ Whi,
                                               const short* __restrict__ Wlo,
                                               const float* __restrict__ bmu,
                                               const float* __restrict__ bvar,
                                               const float* __restrict__ eps,
                                               float* __restrict__ out, int n) {
    int tid = threadIdx.x;
    int w = tid >> 6, lane = tid & 63;
    int m = lane & 15, kb = lane >> 4;
    int row0 = blockIdx.x * 128 + w * 32;

    short8 ah[2][2], al[2][2];
#pragma unroll
    for (int rb = 0; rb < 2; rb++) {
#pragma unroll
        for (int ks = 0; ks < 2; ks++) {
            int grow = row0 + rb * 16 + m;
            float v[8];
            if (grow < n) {
                const float* base = &hagg[(size_t)grow * HDIM + ks * 32 + kb * 8];
                float4 v0 = *(const float4*)base;
                float4 v1 = *(const float4*)(base + 4);
                v[0] = v0.x; v[1] = v0.y; v[2] = v0.z; v[3] = v0.w;
                v[4] = v1.x; v[5] = v1.y; v[6] = v1.z; v[7] = v1.w;
            } else {
#pragma unroll
                for (int jj = 0; jj < 8; jj++) v[jj] = 0.f;
            }
#pragma unroll
            for (int jj = 0; jj < 8; jj++) {
                __hip_bfloat16 h = __float2bfloat16(v[jj]);
                float hf = __bfloat162float(h);
                __hip_bfloat16 l = __float2bfloat16(v[jj] - hf);
                ah[rb][ks][jj] = *(short*)&h;
                al[rb][ks][jj] = *(short*)&l;
            }
        }
    }

    f32x4 acc[2][8];
#pragma unroll
    for (int rb = 0; rb < 2; rb++)
#pragma unroll
        for (int nt = 0; nt < 8; nt++) acc[rb][nt] = (f32x4){0.f, 0.f, 0.f, 0.f};

#pragma unroll
    for (int nt = 0; nt < 8; nt++) {
#pragma unroll
        for (int ks = 0; ks < 2; ks++) {
            const short* bbase = &Whi[(size_t)(nt * 16 + m) * HDIM + ks * 32 + kb * 8];
            const short* lbase = &Wlo[(size_t)(nt * 16 + m) * HDIM + ks * 32 + kb * 8];
            short8 bh = *(const short8*)bbase;
            short8 bl = *(const short8*)lbase;
#pragma unroll
            for (int rb = 0; rb < 2; rb++) {
                acc[rb][nt] = __builtin_amdgcn_mfma_f32_16x16x32_bf16(ah[rb][ks], bh, acc[rb][nt], 0, 0, 0);
                acc[rb][nt] = __builtin_amdgcn_mfma_f32_16x16x32_bf16(al[rb][ks], bh, acc[rb][nt], 0, 0, 0);
                acc[rb][nt] = __builtin_amdgcn_mfma_f32_16x16x32_bf16(ah[rb][ks], bl, acc[rb][nt], 0, 0, 0);
            }
        }
    }

    size_t nh = (size_t)n * HDIM;
#pragma unroll
    for (int rb = 0; rb < 2; rb++) {
#pragma unroll
        for (int nt = 0; nt < 4; nt++) {
            int c = nt * 16 + m;
            float bm = bmu[c], bv = bvar[c];
#pragma unroll
            for (int reg = 0; reg < 4; reg++) {
                int grow = row0 + rb * 16 + kb * 4 + reg;
                if (grow < n) {
                    float mu = acc[rb][nt][reg] + bm;
                    float va = acc[rb][nt + 4][reg] + bv;
                    float zv = fmaxf(va, 0.f) + log1pf(expf(-fabsf(va)));
                    size_t o = (size_t)grow * HDIM + c;
                    float z = mu + zv * eps[o];
                    out[o] = mu;
                    out[nh + o] = zv;
                    out[2 * nh + o] = z;
                }
            }
        }
    }
}

extern "C" void kernel_launch(void* const* d_in, const int* in_sizes, int n_in,
                              void* d_out, int out_size, void* d_ws, size_t ws_size,
                              hipStream_t stream) {
    const float* x    = (const float*)d_in[0];
    const int*   ei   = (const int*)d_in[1];
    const float* W1   = (const float*)d_in[2];
    const float* b1   = (const float*)d_in[3];
    const float* Wmu  = (const float*)d_in[4];
    const float* bmu  = (const float*)d_in[5];
    const float* Wvar = (const float*)d_in[6];
    const float* bvar = (const float*)d_in[7];
    const float* eps  = (const float*)d_in[8];
    float* out = (float*)d_out;

    int n = in_sizes[0] / IDIM;
    int E = in_sizes[1] / 2;
    const int* src = ei;
    const int* dst = ei + E;

    int NB = (n + CB_NODES - 1) >> CB_SH;

    // workspace layout
    char* p = (char*)d_ws;
    u16* bufB   = (u16*)p;               p += (size_t)n * HDIM * 2;      // g2 bf16
    float* hagg = (float*)p;             p += (size_t)n * HDIM * 4;      // hagg fp32
    u16* bufA   = (u16*)hagg;                                            //   alias: g1 bf16
    u32* tmp    = (u32*)hagg;                                            //   alias: packed edges (CSR phase)
    int* srcs   = (int*)p;               p += (size_t)E * 4;             // CSR cols
    short* Btg  = (short*)p;             p += (size_t)IDIM * HDIM * 2;   // W1^T bf16
    short* W2hi = (short*)p;             p += (size_t)128 * HDIM * 2;
    short* W2lo = (short*)p;             p += (size_t)128 * HDIM * 2;
    int* rowptr = (int*)p;               p += (size_t)(n + 1) * 4;
    float* dinv = (float*)p;             p += (size_t)n * 4;
    int* gHist  = (int*)p;               p += 1024 * 4;
    int* gcur   = (int*)p;               p += 1024 * 4;
    int* bucketBase = (int*)p;           p += 1025 * 4;

    // --- CSR build ---
    hipMemsetAsync(gHist, 0, (size_t)NB * sizeof(int), stream);
    k_chist<<<512, 256, 0, stream>>>(dst, gHist, E, NB);
    k_cscan<<<1, 128, 0, stream>>>(gHist, bucketBase, gcur, NB, rowptr, n, E);
    k_partition<<<(E + PCHUNK - 1) / PCHUNK, 256, 0, stream>>>(src, dst, gcur, tmp, E, NB);
    k_finalize<<<NB, 256, 0, stream>>>(tmp, bucketBase, rowptr, dinv, srcs, n);

    // --- weight prep ---
    k_prepB<<<(IDIM * HDIM + 255) / 256, 256, 0, stream>>>(W1, Btg);
    k_prepW2<<<(128 * HDIM + 255) / 256, 256, 0, stream>>>(Wmu, Wvar, W2hi, W2lo);

    // --- layer 1 ---
    k_gemm1<<<(n + GM - 1) / GM, 256, 0, stream>>>(x, Btg, dinv, bufA, n);
    k_gather1<<<(n + 3) / 4, 256, 0, stream>>>(rowptr, srcs, dinv, bufA, b1, bufB, n);

    // --- layer 2: aggregate, then MFMA epilogue GEMM ---
    k_gather2<<<(n + 3) / 4, 256, 0, stream>>>(rowptr, srcs, dinv, bufB, hagg, n);
    k_gemm2<<<(n + 127) / 128, 256, 0, stream>>>(hagg, W2hi, W2lo, bmu, bvar, eps, out, n);
}